// Round 2
// baseline (34.323 us; speedup 1.0000x reference)
//
#include <hip/hip_runtime.h>

// y[b,o,h,w] = sum_j alphas[o,j] * x[b,j,(128-h)&127,(128-w)&127]
// (FFT2 -> complex channel mix -> IFFT2 collapses to flipped-input channel GEMM;
//  betas contributes only to the imaginary part and drops out.)
//
// Orientation: D[w][o] = sum_k X[w][k] * alphas[o][k], flip applied at input
// staging so the epilogue stores are straight float4 (full 64B lines/instr).

using bf16   = __bf16;
using bf16x4 = __attribute__((ext_vector_type(4))) __bf16;
using bf16x8 = __attribute__((ext_vector_type(8))) __bf16;
using f32x4  = __attribute__((ext_vector_type(4))) float;

static __device__ __forceinline__ float f4c(const float4& v, int i) {
    switch (i) { case 0: return v.x; case 1: return v.y; case 2: return v.z; default: return v.w; }
}

// X LDS layout: quad-row q = k>>2 (1024 B each); within a row the bf16x4 for
// (quad q, column w) sits at ((w*8) ^ ((w>>4)<<3) ^ ((q&3)<<3)), elem (k&3)*2.
// XOR swizzle keeps both staging writes and A-frag reads ~2-way (free).
static __device__ __forceinline__ int xoff(int k, int w) {
    const int q = k >> 2;
    return q * 1024 + (((w * 8) ^ ((w >> 4) << 3) ^ ((q & 3) << 3)) | ((k & 3) * 2));
}

__global__ __launch_bounds__(256, 3)
void kk_freqmix_kernel(const float* __restrict__ x,
                       const float* __restrict__ alphas,
                       float* __restrict__ out)
{
    __shared__ unsigned char ldsX[32768];

    const int t   = threadIdx.x;
    const int bid = blockIdx.x;
    const int b   = bid >> 7;           // batch
    const int h   = bid & 127;          // OUTPUT row
    const int hs  = (128 - h) & 127;    // source row in x (h-flip)

    // ---- stage x[b, :, hs, :] (fp32 -> bf16) into LDS with w-flip ----
    const float* xrow = x + ((size_t)b * 128 * 16384) + (size_t)hs * 128;
    #pragma unroll
    for (int it = 0; it < 4; ++it) {
        const int p  = it * 256 + t;
        const int q  = p >> 5;            // k-quad 0..31
        const int n0 = (p & 31) * 4;      // source w base
        const float4 xv0 = *(const float4*)(xrow + (size_t)(4*q + 0) * 16384 + n0);
        const float4 xv1 = *(const float4*)(xrow + (size_t)(4*q + 1) * 16384 + n0);
        const float4 xv2 = *(const float4*)(xrow + (size_t)(4*q + 2) * 16384 + n0);
        const float4 xv3 = *(const float4*)(xrow + (size_t)(4*q + 3) * 16384 + n0);
        #pragma unroll
        for (int i = 0; i < 4; ++i) {
            const int wd = (128 - (n0 + i)) & 127;   // w-flip at input
            bf16x4 v;
            v[0]=(bf16)f4c(xv0,i); v[1]=(bf16)f4c(xv1,i);
            v[2]=(bf16)f4c(xv2,i); v[3]=(bf16)f4c(xv3,i);
            *(bf16x4*)(ldsX + xoff(4*q, wd)) = v;
        }
    }

    __syncthreads();

    // ---- MFMA: D[w][o] = sum_k X[w][k] * alphas[o][k] ----
    const int l  = t & 63;
    const int wv = t >> 6;    // wave 0..3 owns o-slice [wv*32, wv*32+32)
    const int g  = l >> 4;    // lane quadrant (k-chunk selector)
    const int lr = l & 15;

    f32x4 acc[8][2];          // [mf = w-tile][nf = o-tile]
    #pragma unroll
    for (int mf = 0; mf < 8; ++mf)
        #pragma unroll
        for (int nf = 0; nf < 2; ++nf)
            acc[mf][nf] = (f32x4){0.f, 0.f, 0.f, 0.f};

    #pragma unroll
    for (int ks = 0; ks < 4; ++ks) {
        const int kb = ks * 32;
        const int k0 = kb + g * 8;        // sigma(g,v) = g*8+v, same for A and B
        // B-frags: alphas rows straight from global (L2-cached), fp32 -> bf16
        bf16x8 bfr[2];
        #pragma unroll
        for (int nf = 0; nf < 2; ++nf) {
            const int o = wv * 32 + nf * 16 + lr;
            const float4 a0 = *(const float4*)(alphas + o * 128 + k0);
            const float4 a1 = *(const float4*)(alphas + o * 128 + k0 + 4);
            bfr[nf][0]=(bf16)a0.x; bfr[nf][1]=(bf16)a0.y; bfr[nf][2]=(bf16)a0.z; bfr[nf][3]=(bf16)a0.w;
            bfr[nf][4]=(bf16)a1.x; bfr[nf][5]=(bf16)a1.y; bfr[nf][6]=(bf16)a1.z; bfr[nf][7]=(bf16)a1.w;
        }
        // A-frags from LDS: 8 consecutive k at w = mf*16 + lr
        #pragma unroll
        for (int mf = 0; mf < 8; ++mf) {
            const int w = mf * 16 + lr;
            const bf16x4 lo = *(const bf16x4*)(ldsX + xoff(k0,     w));
            const bf16x4 hi = *(const bf16x4*)(ldsX + xoff(k0 + 4, w));
            bf16x8 a;
            a[0]=lo[0]; a[1]=lo[1]; a[2]=lo[2]; a[3]=lo[3];
            a[4]=hi[0]; a[5]=hi[1]; a[6]=hi[2]; a[7]=hi[3];
            acc[mf][0] = __builtin_amdgcn_mfma_f32_16x16x32_bf16(a, bfr[0], acc[mf][0], 0, 0, 0);
            acc[mf][1] = __builtin_amdgcn_mfma_f32_16x16x32_bf16(a, bfr[1], acc[mf][1], 0, 0, 0);
        }
    }

    // ---- epilogue: straight float4 nontemporal stores ----
    // C/D layout: col(o) = lane&15, row(w) = (lane>>4)*4 + reg -> lane holds
    // 4 consecutive w at fixed o; g=0..3 lanes at same lr cover a full 64B line.
    float* const outb = out + ((size_t)b * 128 * 16384) + (size_t)h * 128;
    #pragma unroll
    for (int mf = 0; mf < 8; ++mf) {
        const int w0 = mf * 16 + g * 4;
        #pragma unroll
        for (int nf = 0; nf < 2; ++nf) {
            const int o = wv * 32 + nf * 16 + lr;
            f32x4 v = acc[mf][nf];
            __builtin_nontemporal_store(v, (f32x4*)(outb + (size_t)o * 16384 + w0));
        }
    }
}

extern "C" void kernel_launch(void* const* d_in, const int* in_sizes, int n_in,
                              void* d_out, int out_size, void* d_ws, size_t ws_size,
                              hipStream_t stream) {
    const float* x      = (const float*)d_in[0];
    const float* alphas = (const float*)d_in[1];
    // betas (d_in[2]) provably unused: contributes only to Im(y), dropped by real().
    float* out = (float*)d_out;

    dim3 grid(1024);   // one block per (b, h_out): 8 * 128
    dim3 block(256);
    hipLaunchKernelGGL(kk_freqmix_kernel, grid, block, 0, stream, x, alphas, out);
}

// Round 3
// 32.118 us; speedup vs baseline: 1.0686x; 1.0686x over previous
//
#include <hip/hip_runtime.h>

// y[b,o,h,w] = sum_j alphas[o,j] * x[b,j,(128-h)&127,(128-w)&127]
// (FFT2 -> complex channel mix -> IFFT2 collapses to flipped-input channel GEMM;
//  betas contributes only to the imaginary part and drops out.)
//
// Orientation: D[w][o] = sum_k X[w][k] * alphas[o][k]; spatial flip applied at
// input staging so the epilogue is straight float4 stores (full 64B lines).
// Alphas staged once per block into LDS (round-1-proven pattern).

using bf16   = __bf16;
using bf16x4 = __attribute__((ext_vector_type(4))) __bf16;
using bf16x8 = __attribute__((ext_vector_type(8))) __bf16;
using f32x4  = __attribute__((ext_vector_type(4))) float;

#define LDSA_STRIDE 272            // alphas row: 128*2 B + 16 pad (conflict-free b128 reads)
#define LDSA_BYTES  (128 * 272)    // 34816
#define LDSX_BYTES  (32 * 1024)    // X4 layout, see xoff()

static __device__ __forceinline__ float f4c(const float4& v, int i) {
    switch (i) { case 0: return v.x; case 1: return v.y; case 2: return v.z; default: return v.w; }
}

// X LDS layout: quad-row q = k>>2 (1024 B each); bf16x4 for (q, w) at
//   q*1024 + ((w*8 | (k&3)*2) ^ swz),  swz = (((q>>1)&3) ^ ((w>>4)&3)) << 3.
// The (q>>1)-term spreads the 4 g-groups of an A-frag read (q = 8*ks+2g) over
// distinct banks; the (w>>4)-term spreads staging writes (w stride 4 within an
// instruction -> w bits 4:5 vary) over 16 banks. Both XOR only byte bits 3-4,
// bijective per row; reads see the w-term as a lane-constant, writes see the
// q-term as a lane-constant, so neither perturbs the other.
static __device__ __forceinline__ int xoff(int k, int w) {
    const int q   = k >> 2;
    const int swz = ((((q >> 1) & 3) ^ ((w >> 4) & 3)) << 3);
    return q * 1024 + (((w * 8) | ((k & 3) * 2)) ^ swz);
}

__global__ __launch_bounds__(256, 2)
void kk_freqmix_kernel(const float* __restrict__ x,
                       const float* __restrict__ alphas,
                       float* __restrict__ out)
{
    __shared__ unsigned char lds[LDSA_BYTES + LDSX_BYTES];
    unsigned char* const ldsX = lds + LDSA_BYTES;

    const int t   = threadIdx.x;
    const int bid = blockIdx.x;
    const int b   = bid >> 7;           // batch
    const int h   = bid & 127;          // OUTPUT row
    const int hs  = (128 - h) & 127;    // source row in x (h-flip)

    // ---- stage alphas (fp32 -> bf16) into LDS [o][k], row stride 272 B ----
    #pragma unroll
    for (int it = 0; it < 8; ++it) {
        const int ch  = it * 256 + t;
        const int o   = ch >> 4;
        const int oct = ch & 15;
        const float4 a0 = *(const float4*)(alphas + o * 128 + oct * 8);
        const float4 a1 = *(const float4*)(alphas + o * 128 + oct * 8 + 4);
        bf16x8 v;
        v[0]=(bf16)a0.x; v[1]=(bf16)a0.y; v[2]=(bf16)a0.z; v[3]=(bf16)a0.w;
        v[4]=(bf16)a1.x; v[5]=(bf16)a1.y; v[6]=(bf16)a1.z; v[7]=(bf16)a1.w;
        *(bf16x8*)(lds + o * LDSA_STRIDE + oct * 16) = v;
    }

    // ---- stage x[b, :, hs, :] (fp32 -> bf16) into LDS with w-flip ----
    const float* xrow = x + ((size_t)b * 128 * 16384) + (size_t)hs * 128;
    #pragma unroll
    for (int it = 0; it < 4; ++it) {
        const int p  = it * 256 + t;
        const int q  = p >> 5;            // k-quad 0..31
        const int n0 = (p & 31) * 4;      // source w base
        const float4 xv0 = *(const float4*)(xrow + (size_t)(4*q + 0) * 16384 + n0);
        const float4 xv1 = *(const float4*)(xrow + (size_t)(4*q + 1) * 16384 + n0);
        const float4 xv2 = *(const float4*)(xrow + (size_t)(4*q + 2) * 16384 + n0);
        const float4 xv3 = *(const float4*)(xrow + (size_t)(4*q + 3) * 16384 + n0);
        #pragma unroll
        for (int i = 0; i < 4; ++i) {
            const int wd = (128 - (n0 + i)) & 127;   // w-flip at input
            bf16x4 v;
            v[0]=(bf16)f4c(xv0,i); v[1]=(bf16)f4c(xv1,i);
            v[2]=(bf16)f4c(xv2,i); v[3]=(bf16)f4c(xv3,i);
            *(bf16x4*)(ldsX + xoff(4*q, wd)) = v;
        }
    }

    __syncthreads();

    // ---- MFMA: D[w][o] = sum_k X[w][k] * alphas[o][k] ----
    const int l  = t & 63;
    const int wv = t >> 6;    // wave 0..3 owns o-slice [wv*32, wv*32+32)
    const int g  = l >> 4;    // lane quadrant (k-chunk selector)
    const int lr = l & 15;

    f32x4 acc[8][2];          // [mf = w-tile][nf = o-tile]
    #pragma unroll
    for (int mf = 0; mf < 8; ++mf)
        #pragma unroll
        for (int nf = 0; nf < 2; ++nf)
            acc[mf][nf] = (f32x4){0.f, 0.f, 0.f, 0.f};

    #pragma unroll
    for (int ks = 0; ks < 4; ++ks) {
        const int k0 = ks * 32 + g * 8;   // sigma(g,v) = g*8+v, same for A and B
        // B-frags: alphas rows from LDS (16B contiguous ds_read_b128)
        bf16x8 bfr[2];
        #pragma unroll
        for (int nf = 0; nf < 2; ++nf) {
            const int o = wv * 32 + nf * 16 + lr;
            bfr[nf] = *(const bf16x8*)(lds + o * LDSA_STRIDE + k0 * 2);
        }
        // A-frags from LDS X: two bf16x4 (k0..k0+3 at base, k0+4..k0+7 at +1024)
        #pragma unroll
        for (int mf = 0; mf < 8; ++mf) {
            const int w = mf * 16 + lr;
            const unsigned char* base = ldsX + xoff(k0, w);
            const bf16x4 lo = *(const bf16x4*)(base);
            const bf16x4 hi = *(const bf16x4*)(base + 1024);
            bf16x8 a;
            a[0]=lo[0]; a[1]=lo[1]; a[2]=lo[2]; a[3]=lo[3];
            a[4]=hi[0]; a[5]=hi[1]; a[6]=hi[2]; a[7]=hi[3];
            acc[mf][0] = __builtin_amdgcn_mfma_f32_16x16x32_bf16(a, bfr[0], acc[mf][0], 0, 0, 0);
            acc[mf][1] = __builtin_amdgcn_mfma_f32_16x16x32_bf16(a, bfr[1], acc[mf][1], 0, 0, 0);
        }
    }

    // ---- epilogue: straight float4 nontemporal stores ----
    // C/D layout: col(o) = lane&15, row(w) = (lane>>4)*4 + reg -> lane holds 4
    // consecutive w at fixed o; g=0..3 at same lr cover 16 floats = 64B lines.
    float* const outb = out + ((size_t)b * 128 * 16384) + (size_t)h * 128;
    #pragma unroll
    for (int mf = 0; mf < 8; ++mf) {
        const int w0 = mf * 16 + g * 4;
        #pragma unroll
        for (int nf = 0; nf < 2; ++nf) {
            const int o = wv * 32 + nf * 16 + lr;
            f32x4 v = acc[mf][nf];
            __builtin_nontemporal_store(v, (f32x4*)(outb + (size_t)o * 16384 + w0));
        }
    }
}

extern "C" void kernel_launch(void* const* d_in, const int* in_sizes, int n_in,
                              void* d_out, int out_size, void* d_ws, size_t ws_size,
                              hipStream_t stream) {
    const float* x      = (const float*)d_in[0];
    const float* alphas = (const float*)d_in[1];
    // betas (d_in[2]) provably unused: contributes only to Im(y), dropped by real().
    float* out = (float*)d_out;

    dim3 grid(1024);   // one block per (b, h_out): 8 * 128
    dim3 block(256);
    hipLaunchKernelGGL(kk_freqmix_kernel, grid, block, 0, stream, x, alphas, out);
}